// Round 3
// baseline (307.361 us; speedup 1.0000x reference)
//
#include <hip/hip_runtime.h>
#include <hip/hip_bf16.h>

// BinCat: out[b,i,:] = cats[idx(b,i),:] where
// idx = sum_j (1 - x[b,i,j]) << (19 - j).
// B=4096, I=16, L=20, D=64. Pure gather; memory-bound.
//
// Structure: 64 rows per 256-thread block.
//   Phase 1: wave 0 (t<64) computes one index each, direct from global
//            (5 KB contiguous per block -> L1-resident; avoids LDS fold).
//   Phase 2: all 256 threads copy 64 rows x 256 B, 4 float4 per thread,
//            loads issued before stores for MLP. Nontemporal stores keep
//            L2 free for the cats gather.

#define BATCH 4096
#define I_DIM 16
#define LENGTH 20
#define DIM 64

#define ROWS (BATCH * I_DIM)          // 65536
#define ROWS_PER_BLOCK 64
#define THREADS 256
#define ROWS_PER_THREAD (ROWS_PER_BLOCK * 16 / THREADS)  // 4 float4s/thread

// Native vector type — __builtin_nontemporal_* requires this, not HIP's
// float4 class.
typedef float v4f __attribute__((ext_vector_type(4)));

__global__ __launch_bounds__(THREADS) void bincat_gather(
    const int* __restrict__ x,      // (ROWS, LENGTH)
    const float* __restrict__ cats, // (2^20, DIM)
    float* __restrict__ out)        // (ROWS, DIM)
{
    __shared__ int sidx[ROWS_PER_BLOCK];

    const int t = threadIdx.x;
    const int row0 = blockIdx.x * ROWS_PER_BLOCK;

    // Phase 1: wave 0 folds bits -> indices. Each lane reads its own
    // 20 ints (80 B); wave touches 5 KB contiguous.
    if (t < ROWS_PER_BLOCK) {
        const int* xr = x + (size_t)(row0 + t) * LENGTH;
        int idx = 0;
        #pragma unroll
        for (int j = 0; j < LENGTH; ++j) {
            idx += (1 - __builtin_nontemporal_load(xr + j)) << (LENGTH - 1 - j);
        }
        sidx[t] = idx;
    }
    __syncthreads();

    // Phase 2: gather-copy. 16 threads per row, one v4f each.
    const int pos = t & 15;           // float4 slot within row
    const int rbase = t >> 4;         // 0..15

    v4f v[ROWS_PER_THREAD];
    #pragma unroll
    for (int r = 0; r < ROWS_PER_THREAD; ++r) {
        const int row = rbase + r * 16;
        const v4f* __restrict__ src =
            (const v4f*)(cats + (size_t)sidx[row] * DIM);
        v[r] = src[pos];
    }
    #pragma unroll
    for (int r = 0; r < ROWS_PER_THREAD; ++r) {
        const int row = rbase + r * 16;
        v4f* __restrict__ dst =
            (v4f*)(out + (size_t)(row0 + row) * DIM);
        __builtin_nontemporal_store(v[r], dst + pos);
    }
}

extern "C" void kernel_launch(void* const* d_in, const int* in_sizes, int n_in,
                              void* d_out, int out_size, void* d_ws, size_t ws_size,
                              hipStream_t stream) {
    const int* x = (const int*)d_in[0];        // (4096,16,20) int32
    const float* cats = (const float*)d_in[1]; // (2^20, 64) fp32
    float* out = (float*)d_out;                // (4096,16,64) fp32

    dim3 grid(ROWS / ROWS_PER_BLOCK); // 1024 blocks
    dim3 block(THREADS);
    bincat_gather<<<grid, block, 0, stream>>>(x, cats, out);
}